// Round 15
// baseline (153.860 us; speedup 1.0000x reference)
//
#include <hip/hip_runtime.h>
#include <hip/hip_bf16.h>
#include <math.h>

// Problem constants
constexpr int B_ = 4, T_ = 4096, I_ = 1024, H_ = 16, D_ = 64;
constexpr int M_ = B_ * T_;      // 16384 rows  (b*T + t)
constexpr int N_ = H_ * D_ * 2;  // 2048 cols
constexpr int C_ = 64;           // scan chunks
constexpr int L_ = T_ / C_;      // 64 timesteps per chunk
constexpr int NT_ = 16;          // K-tiles: plain bf16, K=1024

typedef __bf16 bf16x8 __attribute__((ext_vector_type(8)));
typedef float  f32x4  __attribute__((ext_vector_type(4)));

__device__ __forceinline__ float silu_f(float x) {
    return x / (1.0f + __expf(-x));
}

// bf16 RNE helpers
__device__ __forceinline__ ushort f2bf_u(float x) {
    unsigned u = __float_as_uint(x);
    unsigned r = (u + 0x7fffu + ((u >> 16) & 1u)) >> 16;
    return (ushort)r;
}
__device__ __forceinline__ float bfu2f(ushort u) {
    return __uint_as_float(((unsigned)u) << 16);
}

__device__ __forceinline__ void gload_lds16(const void* g, void* l) {
    __builtin_amdgcn_global_load_lds(
        (const __attribute__((address_space(1))) unsigned int*)g,
        (__attribute__((address_space(3))) unsigned int*)l, 16, 0, 0);
}

// Column permutation within each 64-col half-head of B2T (R14-proven):
// GEMM slot (j,l15) holds source col (l15>>1)*8 + j*2 + (l15&1) so the
// epilogue's 4 j-values land at 4 CONSECUTIVE d = (l15>>1)*4 + j.
__device__ __forceinline__ int perm6(int n) {
    int l15 = n & 15, j = (n >> 4) & 3;
    return ((l15 >> 1) << 3) + (j << 1) + (l15 & 1);
}

// ---------------------------------------------------------------------------
// Fused conversion kernel (one dispatch).
// ---------------------------------------------------------------------------
__global__ __launch_bounds__(256) void convert_fused_kernel(
    const float* __restrict__ A,  ushort* __restrict__ A2,
    const float* __restrict__ Bm, ushort* __restrict__ B2T)
{
    __shared__ float tile[64][65];
    const int tid = threadIdx.x;
    if (blockIdx.x < 16384) {
        int idx = blockIdx.x * 256 + tid;
        int m  = idx >> 8;
        int kq = (idx & 255) * 4;
        float4 a = *reinterpret_cast<const float4*>(&A[(size_t)m * 1024 + kq]);
        ushort4 hi;
        hi.x = f2bf_u(a.x);
        hi.y = f2bf_u(a.y);
        hi.z = f2bf_u(a.z);
        hi.w = f2bf_u(a.w);
        *reinterpret_cast<ushort4*>(&A2[(size_t)m * 1024 + kq]) = hi;
    } else {
        int bk = blockIdx.x - 16384;
        const int k0 = (bk & 15) * 64;
        const int n0 = (bk >> 4) * 64;
        #pragma unroll
        for (int p = 0; p < 4; ++p) {
            int f = tid + p * 256;
            int r  = f >> 4;
            int c4 = (f & 15) * 4;
            float4 v = *reinterpret_cast<const float4*>(
                &Bm[(size_t)(k0 + r) * 2048 + n0 + c4]);
            tile[r][c4 + 0] = v.x; tile[r][c4 + 1] = v.y;
            tile[r][c4 + 2] = v.z; tile[r][c4 + 3] = v.w;
        }
        __syncthreads();
        #pragma unroll
        for (int p = 0; p < 4; ++p) {
            int f = tid + p * 256;
            int n  = f >> 4;
            int kq = (f & 15) * 4;
            int pn = perm6(n);
            ushort4 hi;
            hi.x = f2bf_u(tile[kq + 0][pn]);
            hi.y = f2bf_u(tile[kq + 1][pn]);
            hi.z = f2bf_u(tile[kq + 2][pn]);
            hi.w = f2bf_u(tile[kq + 3][pn]);
            *reinterpret_cast<ushort4*>(&B2T[(size_t)(n0 + n) * 1024 + k0 + kq]) = hi;
        }
    }
}

// ---------------------------------------------------------------------------
// 256x256 8-phase MFMA GEMM, plain bf16 (K=1024), R14 structure, with
// XCD remap for A-locality: each XCD owns 8 m-tiles (A 4MB) x all n-panels
// (B 4MB) -> 8MB L2 working set vs 37.5MB with n-panel ownership.
// ---------------------------------------------------------------------------
__device__ __forceinline__ int akof(int t) { return t * 64; }
__device__ __forceinline__ int bkof(int t) { return t * 64; }

#define BARRIER do { asm volatile("" ::: "memory"); \
    __builtin_amdgcn_s_barrier(); \
    asm volatile("" ::: "memory"); } while (0)
#define WAITLGKM asm volatile("s_waitcnt lgkmcnt(0)" ::: "memory")
#define WAITVM(n) asm volatile("s_waitcnt vmcnt(" #n ")" ::: "memory")

#define STAGE(gptr, kb, ldsoff, rs2) do { \
    gload_lds16((gptr) + (kb),         lds + (ldsoff) + tid * 8); \
    gload_lds16((gptr) + (kb) + (rs2), lds + (ldsoff) + 4096 + tid * 8); \
} while (0)

#define RDA(ab, i, kk) (*reinterpret_cast<const bf16x8*>((ab) + (i) * 1024 + ((kk) ? ck1 : ck0)))
#define RDB(bb, j, kk) (*reinterpret_cast<const bf16x8*>((bb) + (j) * 1024 + ((kk) ? ck1 : ck0)))

#define PH_READ_A(ab, ibase) do { \
    _Pragma("unroll") for (int i_ = 0; i_ < 4; ++i_) { \
        a[i_][0] = RDA(ab, (ibase) + i_, 0); \
        a[i_][1] = RDA(ab, (ibase) + i_, 1); } } while (0)
#define PH_READ_B(bb, breg, jbase) do { \
    _Pragma("unroll") for (int j_ = 0; j_ < 2; ++j_) { \
        breg[j_][0] = RDB(bb, (jbase) + j_, 0); \
        breg[j_][1] = RDB(bb, (jbase) + j_, 1); } } while (0)

#define QUAD(IH, BREG, JB) do { \
    __builtin_amdgcn_s_setprio(1); \
    _Pragma("unroll") for (int i_ = 0; i_ < 4; ++i_) \
    _Pragma("unroll") for (int j_ = 0; j_ < 2; ++j_) \
    _Pragma("unroll") for (int k_ = 0; k_ < 2; ++k_) \
        acc[(IH) + i_][(JB) + j_] = __builtin_amdgcn_mfma_f32_16x16x32_bf16( \
            a[i_][k_], BREG[j_][k_], acc[(IH) + i_][(JB) + j_], 0, 0, 0); \
    __builtin_amdgcn_s_setprio(0); \
} while (0)

__global__ __launch_bounds__(512, 2) void gemm_mfma8_kernel(
    const ushort* __restrict__ A2,   // (M, 1024) bf16
    const ushort* __restrict__ B2T,  // (2048 n, 1024 k) bf16, perm6 cols
    const float* __restrict__ qk,    // (H, D)
    ushort* __restrict__ v_buf,      // (B, H, T, D) bf16
    float* __restrict__ s_buf,       // (B, H, T)
    float* __restrict__ agg_m,       // (B,H,C)
    float* __restrict__ agg_u,       // (B,H,C)
    float* __restrict__ agg_w)       // (B,H,C,D)
{
    __shared__ ushort lds[65536];          // 128 KB
    __shared__ float spart[8][128];        // 4 KB
    __shared__ float s_lds[2][256];        // 2 KB

    // XCD remap for A-locality: XCD owns m-tiles [xcd*8, xcd*8+8).
    const int bid = blockIdx.x;
    const int xcd = bid & 7;
    const int q   = bid >> 3;
    const int by  = xcd * 8 + (q & 7);   // m tile 0..63
    const int bx  = q >> 3;              // n panel 0..7 (2 heads per panel)
    const int m0  = by * 256;
    const int n0  = bx * 256;

    const int tid  = threadIdx.x;
    const int lane = tid & 63;
    const int wid  = tid >> 6;
    const int wr = wid >> 2, wc = wid & 3;
    const int l15 = lane & 15, lg = lane >> 4;

    const int row0 = tid >> 3;
    const int ch0  = (tid & 7) ^ (row0 & 7);
    const ushort* pA  = A2  + (size_t)(m0 + row0) * 1024 + ch0 * 8;
    const ushort* pB  = B2T + (size_t)(n0 + row0) * 1024 + ch0 * 8;
    const ushort* pA1 = pA + 128 * 1024;
    const ushort* pB1 = pB + 128 * 1024;

    const int ck0 = ((0 + lg) ^ (l15 & 7)) * 8;
    const int ck1 = ((4 + lg) ^ (l15 & 7)) * 8;
    const ushort* aB0 = lds + (wr * 128 + l15) * 64;
    const ushort* bB0 = lds + 16384 + (wc * 64 + l15) * 64;
    const ushort* aB1 = aB0 + 32768;
    const ushort* bB1 = bB0 + 32768;

    f32x4 acc[8][4];
    #pragma unroll
    for (int i = 0; i < 8; ++i)
        #pragma unroll
        for (int j = 0; j < 4; ++j)
            acc[i][j] = (f32x4){0.f, 0.f, 0.f, 0.f};
    bf16x8 a[4][2], b01[2][2], b23[2][2];

    // ---- prologue
    {
        STAGE(pA,  akof(0), 0,             65536);
        STAGE(pA1, akof(0), 8192,          65536);
        STAGE(pB,  bkof(0), 16384,         65536);
        STAGE(pB1, bkof(0), 16384 + 8192,  65536);
        STAGE(pB,  bkof(1), 49152,         65536);
        STAGE(pA,  akof(1), 32768,         65536);
        WAITVM(4);
        BARRIER;
    }

    // ---- main loop
    #pragma unroll 1
    for (int I = 0; I < NT_ / 2 - 1; ++I) {
        const int t1g = 2 * I + 1, t2g = 2 * I + 2, t3g = 2 * I + 3;
        const int ak1 = akof(t1g), bk1 = bkof(t1g);
        const int ak2 = akof(t2g), bk2 = bkof(t2g);
        const int ak3 = akof(t3g), bk3 = bkof(t3g);
        PH_READ_A(aB0, 0); PH_READ_B(bB0, b01, 0);
        STAGE(pA1, ak1, 32768 + 8192, 65536);
        BARRIER; WAITLGKM; QUAD(0, b01, 0); BARRIER;
        PH_READ_B(bB0, b23, 2);
        STAGE(pB1, bk1, 49152 + 8192, 65536);
        BARRIER; WAITLGKM; QUAD(0, b23, 2); BARRIER;
        PH_READ_A(aB0, 4);
        STAGE(pB, bk2, 16384, 65536);
        BARRIER; WAITLGKM; QUAD(4, b01, 0); BARRIER;
        STAGE(pA, ak2, 0, 65536);
        WAITVM(4);
        BARRIER; QUAD(4, b23, 2); BARRIER;
        PH_READ_A(aB1, 0); PH_READ_B(bB1, b01, 0);
        STAGE(pA1, ak2, 8192, 65536);
        BARRIER; WAITLGKM; QUAD(0, b01, 0); BARRIER;
        PH_READ_B(bB1, b23, 2);
        STAGE(pB1, bk2, 16384 + 8192, 65536);
        BARRIER; WAITLGKM; QUAD(0, b23, 2); BARRIER;
        PH_READ_A(aB1, 4);
        STAGE(pB, bk3, 49152, 65536);
        BARRIER; WAITLGKM; QUAD(4, b01, 0); BARRIER;
        STAGE(pA, ak3, 32768, 65536);
        WAITVM(4);
        BARRIER; QUAD(4, b23, 2); BARRIER;
    }

    // ---- epilogue iteration
    {
        const int t1g = NT_ - 1;
        const int ak1 = akof(t1g), bk1 = bkof(t1g);
        PH_READ_A(aB0, 0); PH_READ_B(bB0, b01, 0);
        STAGE(pA1, ak1, 32768 + 8192, 65536);
        BARRIER; WAITLGKM; QUAD(0, b01, 0); BARRIER;
        PH_READ_B(bB0, b23, 2);
        STAGE(pB1, bk1, 49152 + 8192, 65536);
        BARRIER; WAITLGKM; QUAD(0, b23, 2); BARRIER;
        PH_READ_A(aB0, 4);
        BARRIER; WAITLGKM; QUAD(4, b01, 0); BARRIER;
        WAITVM(0);
        BARRIER; QUAD(4, b23, 2); BARRIER;
        PH_READ_A(aB1, 0); PH_READ_B(bB1, b01, 0);
        BARRIER; WAITLGKM; QUAD(0, b01, 0); BARRIER;
        PH_READ_B(bB1, b23, 2);
        BARRIER; WAITLGKM; QUAD(0, b23, 2); BARRIER;
        PH_READ_A(aB1, 4);
        BARRIER; WAITLGKM; QUAD(4, b01, 0); BARRIER;
        QUAD(4, b23, 2);
    }

    // ---- fused epilogue (permuted d-map: d = (wc&1)*32 + (l15>>1)*4 + j).
    const int hloc  = wc >> 1;
    const int h     = 2 * bx + hloc;
    const int dbase = (wc & 1) * 32 + (l15 >> 1) * 4;
    float qv[4];
    #pragma unroll
    for (int j = 0; j < 4; ++j) qv[j] = qk[h * 64 + dbase + j];
    const bool kcol = ((l15 & 1) == 0);

    #pragma unroll
    for (int i = 0; i < 8; ++i) {
        #pragma unroll
        for (int rr = 0; rr < 4; ++rr) {
            int rloc = wr * 128 + i * 16 + lg * 4 + rr;
            int m = m0 + rloc;
            int b = m >> 12, tt = m & 4095;
            float sv0 = silu_f(acc[i][0][rr]);
            float sv1 = silu_f(acc[i][1][rr]);
            float sv2 = silu_f(acc[i][2][rr]);
            float sv3 = silu_f(acc[i][3][rr]);
            float p = 0.f;
            if (kcol) {
                p = qv[0] * sv0 + qv[1] * sv1 + qv[2] * sv2 + qv[3] * sv3;
            } else {
                ushort4 vs4;
                vs4.x = f2bf_u(sv0); vs4.y = f2bf_u(sv1);
                vs4.z = f2bf_u(sv2); vs4.w = f2bf_u(sv3);
                *reinterpret_cast<ushort4*>(
                    &v_buf[((size_t)(b * H_ + h) * T_ + tt) * D_ + dbase]) = vs4;
            }
            p += __shfl_xor(p, 2);
            p += __shfl_xor(p, 4);
            p += __shfl_xor(p, 8);
            if (l15 == 0) spart[wid][i * 16 + lg * 4 + rr] = p;
        }
    }
    __syncthreads();
    {
        int wr2 = tid >> 8, hl = (tid >> 7) & 1, row = tid & 127;
        int m = m0 + wr2 * 128 + row;
        int b = m >> 12, tt = m & 4095;
        float sval = spart[wr2 * 4 + hl * 2][row] + spart[wr2 * 4 + hl * 2 + 1][row];
        s_buf[(size_t)(b * H_ + 2 * bx + hl) * T_ + tt] = sval;
        s_lds[hl][wr2 * 128 + row] = sval;
    }
    __syncthreads();

    // ---- in-register fused chunk aggregates (R11 structure, permuted d).
    {
        const int b  = m0 >> 12;
        #pragma unroll
        for (int cc = 0; cc < 2; ++cc) {
            const int c_l = wr * 2 + cc;
            const int cg  = ((m0 & 4095) >> 6) + c_l;
            float mm = -INFINITY, u = 0.f;
            float w0 = 0.f, w1 = 0.f, w2 = 0.f, w3 = 0.f;
            #pragma unroll
            for (int ir = 0; ir < 4; ++ir) {
                #pragma unroll
                for (int rr = 0; rr < 4; ++rr) {
                    float s  = s_lds[hloc][c_l * 64 + ir * 16 + lg * 4 + rr];
                    float mn = fmaxf(mm, s);
                    float ea = __expf(mm - mn);
                    float eb = __expf(s - mn);
                    u  = u * ea + eb;
                    w0 = w0 * ea + silu_f(acc[cc * 4 + ir][0][rr]) * eb;
                    w1 = w1 * ea + silu_f(acc[cc * 4 + ir][1][rr]) * eb;
                    w2 = w2 * ea + silu_f(acc[cc * 4 + ir][2][rr]) * eb;
                    w3 = w3 * ea + silu_f(acc[cc * 4 + ir][3][rr]) * eb;
                    mm = mn;
                }
            }
            #pragma unroll
            for (int mk = 16; mk <= 32; mk <<= 1) {
                float om = __shfl_xor(mm, mk);
                float ou = __shfl_xor(u,  mk);
                float o0 = __shfl_xor(w0, mk);
                float o1 = __shfl_xor(w1, mk);
                float o2 = __shfl_xor(w2, mk);
                float o3 = __shfl_xor(w3, mk);
                float mn = fmaxf(mm, om);
                float ea = __expf(mm - mn);
                float eb = __expf(om - mn);
                u  = u * ea + ou * eb;
                w0 = w0 * ea + o0 * eb;
                w1 = w1 * ea + o1 * eb;
                w2 = w2 * ea + o2 * eb;
                w3 = w3 * ea + o3 * eb;
                mm = mn;
            }
            const int base = (b * H_ + h) * C_ + cg;
            if ((wc & 1) == 0 && lane == 0) {
                agg_m[base] = mm;
                agg_u[base] = u;
            }
            if (!kcol && lg == 0) {
                float4 wv = {w0, w1, w2, w3};
                *reinterpret_cast<float4*>(
                    &agg_w[(size_t)base * D_ + dbase]) = wv;
            }
        }
    }
}

// ---------------------------------------------------------------------------
// Fallback f32 GEMM (round-1) used when ws_size is too small.
// ---------------------------------------------------------------------------
#define TILE_M 128
#define TILE_N 128
#define TILE_K 16
__global__ __launch_bounds__(256) void gemm_kv_kernel(
    const float* __restrict__ A, const float* __restrict__ Bm,
    const float* __restrict__ q, ushort* __restrict__ v_buf,
    float* __restrict__ s_buf)
{
    __shared__ float As[TILE_K][TILE_M + 4];
    __shared__ float Bs[TILE_K][TILE_N + 4];
    const int tid = threadIdx.x;
    const int h   = blockIdx.x;
    const int bm  = blockIdx.y;
    const int m0  = bm * TILE_M;
    const int n0  = h * TILE_N;
    const int tx = tid & 15, ty = tid >> 4;
    float acc[8][8];
    #pragma unroll
    for (int i = 0; i < 8; ++i)
        #pragma unroll
        for (int j = 0; j < 8; ++j) acc[i][j] = 0.f;
    for (int k0 = 0; k0 < I_; k0 += TILE_K) {
        #pragma unroll
        for (int p = 0; p < 2; ++p) {
            int f = tid + p * 256;
            int row = f >> 2, kq = (f & 3) * 4;
            float4 av = *reinterpret_cast<const float4*>(
                &A[(size_t)(m0 + row) * I_ + k0 + kq]);
            As[kq + 0][row] = av.x; As[kq + 1][row] = av.y;
            As[kq + 2][row] = av.z; As[kq + 3][row] = av.w;
        }
        #pragma unroll
        for (int p = 0; p < 2; ++p) {
            int f = tid + p * 256;
            int row = f >> 5, c4 = (f & 31) * 4;
            *reinterpret_cast<float4*>(&Bs[row][c4]) =
                *reinterpret_cast<const float4*>(
                    &Bm[(size_t)(k0 + row) * N_ + n0 + c4]);
        }
        __syncthreads();
        #pragma unroll
        for (int kk = 0; kk < TILE_K; ++kk) {
            float4 a0 = *reinterpret_cast<const float4*>(&As[kk][ty * 8]);
            float4 a1 = *reinterpret_cast<const float4*>(&As[kk][ty * 8 + 4]);
            float4 b0 = *reinterpret_cast<const float4*>(&Bs[kk][tx * 8]);
            float4 b1 = *reinterpret_cast<const float4*>(&Bs[kk][tx * 8 + 4]);
            float af[8] = {a0.x, a0.y, a0.z, a0.w, a1.x, a1.y, a1.z, a1.w};
            float bf[8] = {b0.x, b0.y, b0.z, b0.w, b1.x, b1.y, b1.z, b1.w};
            #pragma unroll
            for (int i = 0; i < 8; ++i)
                #pragma unroll
                for (int j = 0; j < 8; ++j)
                    acc[i][j] = fmaf(af[i], bf[j], acc[i][j]);
        }
        __syncthreads();
    }
    float4 qv = *reinterpret_cast<const float4*>(&q[h * D_ + tx * 4]);
    float qf[4] = {qv.x, qv.y, qv.z, qv.w};
    #pragma unroll
    for (int i = 0; i < 8; ++i) {
        int m = m0 + ty * 8 + i;
        int b = m >> 12, t = m & 4095;
        float partial = 0.f;
        #pragma unroll
        for (int j = 0; j < 4; ++j) {
            float kval = silu_f(acc[i][2 * j]);
            float vv = silu_f(acc[i][2 * j + 1]);
            v_buf[((size_t)(b * H_ + h) * T_ + t) * D_ + tx * 4 + j] = f2bf_u(vv);
            partial = fmaf(qf[j], kval, partial);
        }
        #pragma unroll
        for (int mask = 8; mask >= 1; mask >>= 1)
            partial += __shfl_xor(partial, mask, 16);
        if (tx == 0) s_buf[(size_t)(b * H_ + h) * T_ + t] = partial;
    }
}

// ---------------------------------------------------------------------------
// Scan kernels (v_buf bf16). chunk_agg only used on the fallback path.
// ---------------------------------------------------------------------------
__global__ __launch_bounds__(64) void chunk_agg_kernel(
    const float* __restrict__ s_buf, const ushort* __restrict__ v_buf,
    float* __restrict__ agg_m, float* __restrict__ agg_u,
    float* __restrict__ agg_w)
{
    const int x    = blockIdx.x;
    const int c    = x & (C_ - 1);
    const int bh   = x >> 6;
    const int lane = threadIdx.x;
    const float* sp  = s_buf + (size_t)bh * T_ + c * L_;
    const ushort* vp = v_buf + ((size_t)bh * T_ + c * L_) * D_ + lane;
    float m = -INFINITY, u = 0.f, w = 0.f;
    for (int t = 0; t < L_; ++t) {
        float s  = sp[t];
        float vv = bfu2f(vp[(size_t)t * D_]);
        float mn = fmaxf(m, s);
        float ea = __expf(m - mn);
        float eb = __expf(s - mn);
        u = u * ea + eb;
        w = w * ea + vv * eb;
        m = mn;
    }
    if (lane == 0) { agg_m[x] = m; agg_u[x] = u; }
    agg_w[(size_t)x * D_ + lane] = w;
}

__global__ __launch_bounds__(64) void chunk_prefix_kernel(
    float* __restrict__ agg_m, float* __restrict__ agg_u,
    float* __restrict__ agg_w)
{
    const int bh   = blockIdx.x;
    const int lane = threadIdx.x;
    float pm = -INFINITY, pu = 0.f, pw = 0.f;
    #pragma unroll 4
    for (int c = 0; c < C_; ++c) {
        int base = bh * C_ + c;
        float am = agg_m[base];
        float au = agg_u[base];
        float aw = agg_w[(size_t)base * D_ + lane];
        if (lane == 0) { agg_m[base] = pm; agg_u[base] = pu; }
        agg_w[(size_t)base * D_ + lane] = pw;
        float mn = fmaxf(pm, am);
        float ea = __expf(pm - mn);
        float eb = __expf(am - mn);
        pu = pu * ea + au * eb;
        pw = pw * ea + aw * eb;
        pm = mn;
    }
}

// Vectorized apply: thread = (head, d-group of 4). v loads ushort4,
// agg_w/out float4, cross-head sum via shfl_xor(16/32) butterfly.
__global__ __launch_bounds__(256) void scan_apply_kernel(
    const float* __restrict__ s_buf, const ushort* __restrict__ v_buf,
    const float* __restrict__ agg_m, const float* __restrict__ agg_u,
    const float* __restrict__ agg_w, float* __restrict__ out)
{
    __shared__ float part[4][8][64];
    const int bx   = blockIdx.x;
    const int b    = bx >> 6;
    const int c    = bx & (C_ - 1);
    const int w    = threadIdx.x >> 6;
    const int lane = threadIdx.x & 63;
    const int hsub = lane >> 4;          // 0..3
    const int dg   = lane & 15;          // d-group: d = dg*4..dg*4+3
    const int h    = w * 4 + hsub;
    const int base = (b * H_ + h) * C_ + c;

    float m = agg_m[base];
    float u = agg_u[base];
    float4 w4 = *reinterpret_cast<const float4*>(&agg_w[(size_t)base * D_ + dg * 4]);

    const int t0 = c * L_;
    const float*  sp = s_buf + (size_t)(b * H_ + h) * T_;
    const ushort* vp = v_buf + ((size_t)(b * H_ + h) * T_) * D_ + dg * 4;

    for (int g = 0; g < L_ / 8; ++g) {
        #pragma unroll
        for (int qq = 0; qq < 8; ++qq) {
            int t = t0 + g * 8 + qq;
            float s = sp[t];
            ushort4 vv = *reinterpret_cast<const ushort4*>(&vp[(size_t)t * D_]);
            float mn = fmaxf(m, s);
            float ea = __expf(m - mn);
            float eb = __expf(s - mn);
            u    = u    * ea + eb;
            w4.x = w4.x * ea + bfu2f(vv.x) * eb;
            w4.y = w4.y * ea + bfu2f(vv.y) * eb;
            w4.z = w4.z * ea + bfu2f(vv.z) * eb;
            w4.w = w4.w * ea + bfu2f(vv.w) * eb;
            m = mn;
            float ru = 1.0f / u;
            float a0 = w4.x * ru, a1 = w4.y * ru, a2 = w4.z * ru, a3 = w4.w * ru;
            a0 += __shfl_xor(a0, 16); a1 += __shfl_xor(a1, 16);
            a2 += __shfl_xor(a2, 16); a3 += __shfl_xor(a3, 16);
            a0 += __shfl_xor(a0, 32); a1 += __shfl_xor(a1, 32);
            a2 += __shfl_xor(a2, 32); a3 += __shfl_xor(a3, 32);
            if (hsub == 0) {
                float4 av = {a0, a1, a2, a3};
                *reinterpret_cast<float4*>(&part[w][qq][dg * 4]) = av;
            }
        }
        __syncthreads();
        if (threadIdx.x < 128) {
            int tt = threadIdx.x >> 4, dgg = threadIdx.x & 15;
            float4 p0 = *reinterpret_cast<const float4*>(&part[0][tt][dgg * 4]);
            float4 p1 = *reinterpret_cast<const float4*>(&part[1][tt][dgg * 4]);
            float4 p2 = *reinterpret_cast<const float4*>(&part[2][tt][dgg * 4]);
            float4 p3 = *reinterpret_cast<const float4*>(&part[3][tt][dgg * 4]);
            float4 o;
            o.x = (p0.x + p1.x + p2.x + p3.x) * (1.f / 16.f);
            o.y = (p0.y + p1.y + p2.y + p3.y) * (1.f / 16.f);
            o.z = (p0.z + p1.z + p2.z + p3.z) * (1.f / 16.f);
            o.w = (p0.w + p1.w + p2.w + p3.w) * (1.f / 16.f);
            *reinterpret_cast<float4*>(
                &out[((size_t)b * T_ + (t0 + g * 8 + tt)) * D_ + dgg * 4]) = o;
        }
        __syncthreads();
    }
}

// ---------------------------------------------------------------------------
extern "C" void kernel_launch(void* const* d_in, const int* in_sizes, int n_in,
                              void* d_out, int out_size, void* d_ws, size_t ws_size,
                              hipStream_t stream) {
    const float* A  = (const float*)d_in[0];  // inputs (B,T,I)
    const float* Bm = (const float*)d_in[1];  // kv_kernel (I,H,D,2)
    const float* q  = (const float*)d_in[2];  // q_kernel (H,D)
    float* out = (float*)d_out;

    // workspace layout: v (bf16) | s | agg_m | agg_u | agg_w | A2 | B2T
    ushort* v_buf = (ushort*)d_ws;
    float*  s_buf = (float*)(v_buf + (size_t)B_ * H_ * T_ * D_);
    float*  agg_m = s_buf + (size_t)B_ * H_ * T_;
    float*  agg_u = agg_m + B_ * H_ * C_;
    float*  agg_w = agg_u + B_ * H_ * C_;
    ushort* A2    = (ushort*)(agg_w + (size_t)B_ * H_ * C_ * D_);
    ushort* B2T   = A2 + (size_t)M_ * 1024;

    size_t need = (size_t)B_ * H_ * T_ * D_ * 2
                + ((size_t)262144 + 4096 + 4096 + 262144) * 4
                + ((size_t)M_ * 1024 + (size_t)2048 * 1024) * 2;

    if (ws_size >= need) {
        convert_fused_kernel<<<16896, 256, 0, stream>>>(A, A2, Bm, B2T);
        gemm_mfma8_kernel<<<512, 512, 0, stream>>>(A2, B2T, q, v_buf, s_buf,
                                                   agg_m, agg_u, agg_w);
    } else {
        dim3 ggrid(H_, M_ / TILE_M);
        gemm_kv_kernel<<<ggrid, 256, 0, stream>>>(A, Bm, q, v_buf, s_buf);
        chunk_agg_kernel<<<B_ * H_ * C_, 64, 0, stream>>>(s_buf, v_buf,
                                                          agg_m, agg_u, agg_w);
    }
    chunk_prefix_kernel<<<B_ * H_, 64, 0, stream>>>(agg_m, agg_u, agg_w);
    scan_apply_kernel<<<B_ * C_, 256, 0, stream>>>(s_buf, v_buf, agg_m, agg_u, agg_w, out);
}

// Round 16
// 142.905 us; speedup vs baseline: 1.0767x; 1.0767x over previous
//
#include <hip/hip_runtime.h>
#include <hip/hip_bf16.h>
#include <math.h>

// Problem constants
constexpr int B_ = 4, T_ = 4096, I_ = 1024, H_ = 16, D_ = 64;
constexpr int M_ = B_ * T_;      // 16384 rows  (b*T + t)
constexpr int N_ = H_ * D_ * 2;  // 2048 cols
constexpr int C_ = 64;           // scan chunks
constexpr int L_ = T_ / C_;      // 64 timesteps per chunk
constexpr int NT_ = 16;          // K-tiles: plain bf16, K=1024

typedef __bf16 bf16x8 __attribute__((ext_vector_type(8)));
typedef float  f32x4  __attribute__((ext_vector_type(4)));

__device__ __forceinline__ float silu_f(float x) {
    return x / (1.0f + __expf(-x));
}

// bf16 RNE helpers
__device__ __forceinline__ ushort f2bf_u(float x) {
    unsigned u = __float_as_uint(x);
    unsigned r = (u + 0x7fffu + ((u >> 16) & 1u)) >> 16;
    return (ushort)r;
}
__device__ __forceinline__ float bfu2f(ushort u) {
    return __uint_as_float(((unsigned)u) << 16);
}

__device__ __forceinline__ void gload_lds16(const void* g, void* l) {
    __builtin_amdgcn_global_load_lds(
        (const __attribute__((address_space(1))) unsigned int*)g,
        (__attribute__((address_space(3))) unsigned int*)l, 16, 0, 0);
}

// Column permutation within each 64-col half-head of B2T (R14-proven):
// GEMM slot (j,l15) holds source col (l15>>1)*8 + j*2 + (l15&1) so the
// epilogue's 4 j-values land at 4 CONSECUTIVE d = (l15>>1)*4 + j.
__device__ __forceinline__ int perm6(int n) {
    int l15 = n & 15, j = (n >> 4) & 3;
    return ((l15 >> 1) << 3) + (j << 1) + (l15 & 1);
}

// ---------------------------------------------------------------------------
// Fused conversion kernel (one dispatch).
// ---------------------------------------------------------------------------
__global__ __launch_bounds__(256) void convert_fused_kernel(
    const float* __restrict__ A,  ushort* __restrict__ A2,
    const float* __restrict__ Bm, ushort* __restrict__ B2T)
{
    __shared__ float tile[64][65];
    const int tid = threadIdx.x;
    if (blockIdx.x < 16384) {
        int idx = blockIdx.x * 256 + tid;
        int m  = idx >> 8;
        int kq = (idx & 255) * 4;
        float4 a = *reinterpret_cast<const float4*>(&A[(size_t)m * 1024 + kq]);
        ushort4 hi;
        hi.x = f2bf_u(a.x);
        hi.y = f2bf_u(a.y);
        hi.z = f2bf_u(a.z);
        hi.w = f2bf_u(a.w);
        *reinterpret_cast<ushort4*>(&A2[(size_t)m * 1024 + kq]) = hi;
    } else {
        int bk = blockIdx.x - 16384;
        const int k0 = (bk & 15) * 64;
        const int n0 = (bk >> 4) * 64;
        #pragma unroll
        for (int p = 0; p < 4; ++p) {
            int f = tid + p * 256;
            int r  = f >> 4;
            int c4 = (f & 15) * 4;
            float4 v = *reinterpret_cast<const float4*>(
                &Bm[(size_t)(k0 + r) * 2048 + n0 + c4]);
            tile[r][c4 + 0] = v.x; tile[r][c4 + 1] = v.y;
            tile[r][c4 + 2] = v.z; tile[r][c4 + 3] = v.w;
        }
        __syncthreads();
        #pragma unroll
        for (int p = 0; p < 4; ++p) {
            int f = tid + p * 256;
            int n  = f >> 4;
            int kq = (f & 15) * 4;
            int pn = perm6(n);
            ushort4 hi;
            hi.x = f2bf_u(tile[kq + 0][pn]);
            hi.y = f2bf_u(tile[kq + 1][pn]);
            hi.z = f2bf_u(tile[kq + 2][pn]);
            hi.w = f2bf_u(tile[kq + 3][pn]);
            *reinterpret_cast<ushort4*>(&B2T[(size_t)(n0 + n) * 1024 + k0 + kq]) = hi;
        }
    }
}

// ---------------------------------------------------------------------------
// 256x256 8-phase MFMA GEMM, plain bf16 (K=1024), R14 structure, with
// XCD remap for A-locality (R15-proven: FETCH 135->49 MB).
// ---------------------------------------------------------------------------
__device__ __forceinline__ int akof(int t) { return t * 64; }
__device__ __forceinline__ int bkof(int t) { return t * 64; }

#define BARRIER do { asm volatile("" ::: "memory"); \
    __builtin_amdgcn_s_barrier(); \
    asm volatile("" ::: "memory"); } while (0)
#define WAITLGKM asm volatile("s_waitcnt lgkmcnt(0)" ::: "memory")
#define WAITVM(n) asm volatile("s_waitcnt vmcnt(" #n ")" ::: "memory")

#define STAGE(gptr, kb, ldsoff, rs2) do { \
    gload_lds16((gptr) + (kb),         lds + (ldsoff) + tid * 8); \
    gload_lds16((gptr) + (kb) + (rs2), lds + (ldsoff) + 4096 + tid * 8); \
} while (0)

#define RDA(ab, i, kk) (*reinterpret_cast<const bf16x8*>((ab) + (i) * 1024 + ((kk) ? ck1 : ck0)))
#define RDB(bb, j, kk) (*reinterpret_cast<const bf16x8*>((bb) + (j) * 1024 + ((kk) ? ck1 : ck0)))

#define PH_READ_A(ab, ibase) do { \
    _Pragma("unroll") for (int i_ = 0; i_ < 4; ++i_) { \
        a[i_][0] = RDA(ab, (ibase) + i_, 0); \
        a[i_][1] = RDA(ab, (ibase) + i_, 1); } } while (0)
#define PH_READ_B(bb, breg, jbase) do { \
    _Pragma("unroll") for (int j_ = 0; j_ < 2; ++j_) { \
        breg[j_][0] = RDB(bb, (jbase) + j_, 0); \
        breg[j_][1] = RDB(bb, (jbase) + j_, 1); } } while (0)

#define QUAD(IH, BREG, JB) do { \
    __builtin_amdgcn_s_setprio(1); \
    _Pragma("unroll") for (int i_ = 0; i_ < 4; ++i_) \
    _Pragma("unroll") for (int j_ = 0; j_ < 2; ++j_) \
    _Pragma("unroll") for (int k_ = 0; k_ < 2; ++k_) \
        acc[(IH) + i_][(JB) + j_] = __builtin_amdgcn_mfma_f32_16x16x32_bf16( \
            a[i_][k_], BREG[j_][k_], acc[(IH) + i_][(JB) + j_], 0, 0, 0); \
    __builtin_amdgcn_s_setprio(0); \
} while (0)

__global__ __launch_bounds__(512, 2) void gemm_mfma8_kernel(
    const ushort* __restrict__ A2,   // (M, 1024) bf16
    const ushort* __restrict__ B2T,  // (2048 n, 1024 k) bf16, perm6 cols
    const float* __restrict__ qk,    // (H, D)
    ushort* __restrict__ v_buf,      // (B, H, T, D) bf16
    float* __restrict__ s_buf,       // (B, H, T)
    float* __restrict__ agg_m,       // (B,H,C)
    float* __restrict__ agg_u,       // (B,H,C)
    float* __restrict__ agg_w)       // (B,H,C,D)
{
    __shared__ ushort lds[65536];          // 128 KB
    __shared__ float spart[8][128];        // 4 KB
    __shared__ float s_lds[2][256];        // 2 KB

    // XCD remap for A-locality: XCD owns m-tiles [xcd*8, xcd*8+8).
    const int bid = blockIdx.x;
    const int xcd = bid & 7;
    const int q   = bid >> 3;
    const int by  = xcd * 8 + (q & 7);   // m tile 0..63
    const int bx  = q >> 3;              // n panel 0..7 (2 heads per panel)
    const int m0  = by * 256;
    const int n0  = bx * 256;

    const int tid  = threadIdx.x;
    const int lane = tid & 63;
    const int wid  = tid >> 6;
    const int wr = wid >> 2, wc = wid & 3;
    const int l15 = lane & 15, lg = lane >> 4;

    const int row0 = tid >> 3;
    const int ch0  = (tid & 7) ^ (row0 & 7);
    const ushort* pA  = A2  + (size_t)(m0 + row0) * 1024 + ch0 * 8;
    const ushort* pB  = B2T + (size_t)(n0 + row0) * 1024 + ch0 * 8;
    const ushort* pA1 = pA + 128 * 1024;
    const ushort* pB1 = pB + 128 * 1024;

    const int ck0 = ((0 + lg) ^ (l15 & 7)) * 8;
    const int ck1 = ((4 + lg) ^ (l15 & 7)) * 8;
    const ushort* aB0 = lds + (wr * 128 + l15) * 64;
    const ushort* bB0 = lds + 16384 + (wc * 64 + l15) * 64;
    const ushort* aB1 = aB0 + 32768;
    const ushort* bB1 = bB0 + 32768;

    f32x4 acc[8][4];
    #pragma unroll
    for (int i = 0; i < 8; ++i)
        #pragma unroll
        for (int j = 0; j < 4; ++j)
            acc[i][j] = (f32x4){0.f, 0.f, 0.f, 0.f};
    bf16x8 a[4][2], b01[2][2], b23[2][2];

    // ---- prologue
    {
        STAGE(pA,  akof(0), 0,             65536);
        STAGE(pA1, akof(0), 8192,          65536);
        STAGE(pB,  bkof(0), 16384,         65536);
        STAGE(pB1, bkof(0), 16384 + 8192,  65536);
        STAGE(pB,  bkof(1), 49152,         65536);
        STAGE(pA,  akof(1), 32768,         65536);
        WAITVM(4);
        BARRIER;
    }

    // ---- main loop
    #pragma unroll 1
    for (int I = 0; I < NT_ / 2 - 1; ++I) {
        const int t1g = 2 * I + 1, t2g = 2 * I + 2, t3g = 2 * I + 3;
        const int ak1 = akof(t1g), bk1 = bkof(t1g);
        const int ak2 = akof(t2g), bk2 = bkof(t2g);
        const int ak3 = akof(t3g), bk3 = bkof(t3g);
        PH_READ_A(aB0, 0); PH_READ_B(bB0, b01, 0);
        STAGE(pA1, ak1, 32768 + 8192, 65536);
        BARRIER; WAITLGKM; QUAD(0, b01, 0); BARRIER;
        PH_READ_B(bB0, b23, 2);
        STAGE(pB1, bk1, 49152 + 8192, 65536);
        BARRIER; WAITLGKM; QUAD(0, b23, 2); BARRIER;
        PH_READ_A(aB0, 4);
        STAGE(pB, bk2, 16384, 65536);
        BARRIER; WAITLGKM; QUAD(4, b01, 0); BARRIER;
        STAGE(pA, ak2, 0, 65536);
        WAITVM(4);
        BARRIER; QUAD(4, b23, 2); BARRIER;
        PH_READ_A(aB1, 0); PH_READ_B(bB1, b01, 0);
        STAGE(pA1, ak2, 8192, 65536);
        BARRIER; WAITLGKM; QUAD(0, b01, 0); BARRIER;
        PH_READ_B(bB1, b23, 2);
        STAGE(pB1, bk2, 16384 + 8192, 65536);
        BARRIER; WAITLGKM; QUAD(0, b23, 2); BARRIER;
        PH_READ_A(aB1, 4);
        STAGE(pB, bk3, 49152, 65536);
        BARRIER; WAITLGKM; QUAD(4, b01, 0); BARRIER;
        STAGE(pA, ak3, 32768, 65536);
        WAITVM(4);
        BARRIER; QUAD(4, b23, 2); BARRIER;
    }

    // ---- epilogue iteration
    {
        const int t1g = NT_ - 1;
        const int ak1 = akof(t1g), bk1 = bkof(t1g);
        PH_READ_A(aB0, 0); PH_READ_B(bB0, b01, 0);
        STAGE(pA1, ak1, 32768 + 8192, 65536);
        BARRIER; WAITLGKM; QUAD(0, b01, 0); BARRIER;
        PH_READ_B(bB0, b23, 2);
        STAGE(pB1, bk1, 49152 + 8192, 65536);
        BARRIER; WAITLGKM; QUAD(0, b23, 2); BARRIER;
        PH_READ_A(aB0, 4);
        BARRIER; WAITLGKM; QUAD(4, b01, 0); BARRIER;
        WAITVM(0);
        BARRIER; QUAD(4, b23, 2); BARRIER;
        PH_READ_A(aB1, 0); PH_READ_B(bB1, b01, 0);
        BARRIER; WAITLGKM; QUAD(0, b01, 0); BARRIER;
        PH_READ_B(bB1, b23, 2);
        BARRIER; WAITLGKM; QUAD(0, b23, 2); BARRIER;
        PH_READ_A(aB1, 4);
        BARRIER; WAITLGKM; QUAD(4, b01, 0); BARRIER;
        QUAD(4, b23, 2);
    }

    // ---- fused epilogue (permuted d-map: d = (wc&1)*32 + (l15>>1)*4 + j).
    const int hloc  = wc >> 1;
    const int h     = 2 * bx + hloc;
    const int dbase = (wc & 1) * 32 + (l15 >> 1) * 4;
    float qv[4];
    #pragma unroll
    for (int j = 0; j < 4; ++j) qv[j] = qk[h * 64 + dbase + j];
    const bool kcol = ((l15 & 1) == 0);

    #pragma unroll
    for (int i = 0; i < 8; ++i) {
        #pragma unroll
        for (int rr = 0; rr < 4; ++rr) {
            int rloc = wr * 128 + i * 16 + lg * 4 + rr;
            int m = m0 + rloc;
            int b = m >> 12, tt = m & 4095;
            float sv0 = silu_f(acc[i][0][rr]);
            float sv1 = silu_f(acc[i][1][rr]);
            float sv2 = silu_f(acc[i][2][rr]);
            float sv3 = silu_f(acc[i][3][rr]);
            float p = 0.f;
            if (kcol) {
                p = qv[0] * sv0 + qv[1] * sv1 + qv[2] * sv2 + qv[3] * sv3;
            } else {
                ushort4 vs4;
                vs4.x = f2bf_u(sv0); vs4.y = f2bf_u(sv1);
                vs4.z = f2bf_u(sv2); vs4.w = f2bf_u(sv3);
                *reinterpret_cast<ushort4*>(
                    &v_buf[((size_t)(b * H_ + h) * T_ + tt) * D_ + dbase]) = vs4;
            }
            p += __shfl_xor(p, 2);
            p += __shfl_xor(p, 4);
            p += __shfl_xor(p, 8);
            if (l15 == 0) spart[wid][i * 16 + lg * 4 + rr] = p;
        }
    }
    __syncthreads();
    {
        int wr2 = tid >> 8, hl = (tid >> 7) & 1, row = tid & 127;
        int m = m0 + wr2 * 128 + row;
        int b = m >> 12, tt = m & 4095;
        float sval = spart[wr2 * 4 + hl * 2][row] + spart[wr2 * 4 + hl * 2 + 1][row];
        s_buf[(size_t)(b * H_ + 2 * bx + hl) * T_ + tt] = sval;
        s_lds[hl][wr2 * 128 + row] = sval;
    }
    __syncthreads();

    // ---- in-register fused chunk aggregates (R11 structure, permuted d).
    {
        const int b  = m0 >> 12;
        #pragma unroll
        for (int cc = 0; cc < 2; ++cc) {
            const int c_l = wr * 2 + cc;
            const int cg  = ((m0 & 4095) >> 6) + c_l;
            float mm = -INFINITY, u = 0.f;
            float w0 = 0.f, w1 = 0.f, w2 = 0.f, w3 = 0.f;
            #pragma unroll
            for (int ir = 0; ir < 4; ++ir) {
                #pragma unroll
                for (int rr = 0; rr < 4; ++rr) {
                    float s  = s_lds[hloc][c_l * 64 + ir * 16 + lg * 4 + rr];
                    float mn = fmaxf(mm, s);
                    float ea = __expf(mm - mn);
                    float eb = __expf(s - mn);
                    u  = u * ea + eb;
                    w0 = w0 * ea + silu_f(acc[cc * 4 + ir][0][rr]) * eb;
                    w1 = w1 * ea + silu_f(acc[cc * 4 + ir][1][rr]) * eb;
                    w2 = w2 * ea + silu_f(acc[cc * 4 + ir][2][rr]) * eb;
                    w3 = w3 * ea + silu_f(acc[cc * 4 + ir][3][rr]) * eb;
                    mm = mn;
                }
            }
            #pragma unroll
            for (int mk = 16; mk <= 32; mk <<= 1) {
                float om = __shfl_xor(mm, mk);
                float ou = __shfl_xor(u,  mk);
                float o0 = __shfl_xor(w0, mk);
                float o1 = __shfl_xor(w1, mk);
                float o2 = __shfl_xor(w2, mk);
                float o3 = __shfl_xor(w3, mk);
                float mn = fmaxf(mm, om);
                float ea = __expf(mm - mn);
                float eb = __expf(om - mn);
                u  = u * ea + ou * eb;
                w0 = w0 * ea + o0 * eb;
                w1 = w1 * ea + o1 * eb;
                w2 = w2 * ea + o2 * eb;
                w3 = w3 * ea + o3 * eb;
                mm = mn;
            }
            const int base = (b * H_ + h) * C_ + cg;
            if ((wc & 1) == 0 && lane == 0) {
                agg_m[base] = mm;
                agg_u[base] = u;
            }
            if (!kcol && lg == 0) {
                float4 wv = {w0, w1, w2, w3};
                *reinterpret_cast<float4*>(
                    &agg_w[(size_t)base * D_ + dbase]) = wv;
            }
        }
    }
}

// ---------------------------------------------------------------------------
// Fallback f32 GEMM (round-1) used when ws_size is too small.
// ---------------------------------------------------------------------------
#define TILE_M 128
#define TILE_N 128
#define TILE_K 16
__global__ __launch_bounds__(256) void gemm_kv_kernel(
    const float* __restrict__ A, const float* __restrict__ Bm,
    const float* __restrict__ q, ushort* __restrict__ v_buf,
    float* __restrict__ s_buf)
{
    __shared__ float As[TILE_K][TILE_M + 4];
    __shared__ float Bs[TILE_K][TILE_N + 4];
    const int tid = threadIdx.x;
    const int h   = blockIdx.x;
    const int bm  = blockIdx.y;
    const int m0  = bm * TILE_M;
    const int n0  = h * TILE_N;
    const int tx = tid & 15, ty = tid >> 4;
    float acc[8][8];
    #pragma unroll
    for (int i = 0; i < 8; ++i)
        #pragma unroll
        for (int j = 0; j < 8; ++j) acc[i][j] = 0.f;
    for (int k0 = 0; k0 < I_; k0 += TILE_K) {
        #pragma unroll
        for (int p = 0; p < 2; ++p) {
            int f = tid + p * 256;
            int row = f >> 2, kq = (f & 3) * 4;
            float4 av = *reinterpret_cast<const float4*>(
                &A[(size_t)(m0 + row) * I_ + k0 + kq]);
            As[kq + 0][row] = av.x; As[kq + 1][row] = av.y;
            As[kq + 2][row] = av.z; As[kq + 3][row] = av.w;
        }
        #pragma unroll
        for (int p = 0; p < 2; ++p) {
            int f = tid + p * 256;
            int row = f >> 5, c4 = (f & 31) * 4;
            *reinterpret_cast<float4*>(&Bs[row][c4]) =
                *reinterpret_cast<const float4*>(
                    &Bm[(size_t)(k0 + row) * N_ + n0 + c4]);
        }
        __syncthreads();
        #pragma unroll
        for (int kk = 0; kk < TILE_K; ++kk) {
            float4 a0 = *reinterpret_cast<const float4*>(&As[kk][ty * 8]);
            float4 a1 = *reinterpret_cast<const float4*>(&As[kk][ty * 8 + 4]);
            float4 b0 = *reinterpret_cast<const float4*>(&Bs[kk][tx * 8]);
            float4 b1 = *reinterpret_cast<const float4*>(&Bs[kk][tx * 8 + 4]);
            float af[8] = {a0.x, a0.y, a0.z, a0.w, a1.x, a1.y, a1.z, a1.w};
            float bf[8] = {b0.x, b0.y, b0.z, b0.w, b1.x, b1.y, b1.z, b1.w};
            #pragma unroll
            for (int i = 0; i < 8; ++i)
                #pragma unroll
                for (int j = 0; j < 8; ++j)
                    acc[i][j] = fmaf(af[i], bf[j], acc[i][j]);
        }
        __syncthreads();
    }
    float4 qv = *reinterpret_cast<const float4*>(&q[h * D_ + tx * 4]);
    float qf[4] = {qv.x, qv.y, qv.z, qv.w};
    #pragma unroll
    for (int i = 0; i < 8; ++i) {
        int m = m0 + ty * 8 + i;
        int b = m >> 12, t = m & 4095;
        float partial = 0.f;
        #pragma unroll
        for (int j = 0; j < 4; ++j) {
            float kval = silu_f(acc[i][2 * j]);
            float vv = silu_f(acc[i][2 * j + 1]);
            v_buf[((size_t)(b * H_ + h) * T_ + t) * D_ + tx * 4 + j] = f2bf_u(vv);
            partial = fmaf(qf[j], kval, partial);
        }
        #pragma unroll
        for (int mask = 8; mask >= 1; mask >>= 1)
            partial += __shfl_xor(partial, mask, 16);
        if (tx == 0) s_buf[(size_t)(b * H_ + h) * T_ + t] = partial;
    }
}

// ---------------------------------------------------------------------------
// Scan kernels (v_buf bf16). chunk_agg only used on the fallback path.
// ---------------------------------------------------------------------------
__global__ __launch_bounds__(64) void chunk_agg_kernel(
    const float* __restrict__ s_buf, const ushort* __restrict__ v_buf,
    float* __restrict__ agg_m, float* __restrict__ agg_u,
    float* __restrict__ agg_w)
{
    const int x    = blockIdx.x;
    const int c    = x & (C_ - 1);
    const int bh   = x >> 6;
    const int lane = threadIdx.x;
    const float* sp  = s_buf + (size_t)bh * T_ + c * L_;
    const ushort* vp = v_buf + ((size_t)bh * T_ + c * L_) * D_ + lane;
    float m = -INFINITY, u = 0.f, w = 0.f;
    for (int t = 0; t < L_; ++t) {
        float s  = sp[t];
        float vv = bfu2f(vp[(size_t)t * D_]);
        float mn = fmaxf(m, s);
        float ea = __expf(m - mn);
        float eb = __expf(s - mn);
        u = u * ea + eb;
        w = w * ea + vv * eb;
        m = mn;
    }
    if (lane == 0) { agg_m[x] = m; agg_u[x] = u; }
    agg_w[(size_t)x * D_ + lane] = w;
}

__global__ __launch_bounds__(64) void chunk_prefix_kernel(
    float* __restrict__ agg_m, float* __restrict__ agg_u,
    float* __restrict__ agg_w)
{
    const int bh   = blockIdx.x;
    const int lane = threadIdx.x;
    float pm = -INFINITY, pu = 0.f, pw = 0.f;
    #pragma unroll 4
    for (int c = 0; c < C_; ++c) {
        int base = bh * C_ + c;
        float am = agg_m[base];
        float au = agg_u[base];
        float aw = agg_w[(size_t)base * D_ + lane];
        if (lane == 0) { agg_m[base] = pm; agg_u[base] = pu; }
        agg_w[(size_t)base * D_ + lane] = pw;
        float mn = fmaxf(pm, am);
        float ea = __expf(pm - mn);
        float eb = __expf(am - mn);
        pu = pu * ea + au * eb;
        pw = pw * ea + aw * eb;
        pm = mn;
    }
}

// R14-proven apply: thread = 4 heads x 1 d; bulk LDS reduce per 8 t.
__global__ __launch_bounds__(256) void scan_apply_kernel(
    const float* __restrict__ s_buf, const ushort* __restrict__ v_buf,
    const float* __restrict__ agg_m, const float* __restrict__ agg_u,
    const float* __restrict__ agg_w, float* __restrict__ out)
{
    __shared__ float part[4][8][64];
    const int bx   = blockIdx.x;
    const int b    = bx >> 6;
    const int c    = bx & (C_ - 1);
    const int w    = threadIdx.x >> 6;
    const int lane = threadIdx.x & 63;
    float m[4], u[4], ws[4];
    #pragma unroll
    for (int j = 0; j < 4; ++j) {
        int h = w * 4 + j;
        int base = (b * H_ + h) * C_ + c;
        m[j]  = agg_m[base];
        u[j]  = agg_u[base];
        ws[j] = agg_w[(size_t)base * D_ + lane];
    }
    const int t0 = c * L_;
    for (int g = 0; g < L_ / 8; ++g) {
        #pragma unroll
        for (int qq = 0; qq < 8; ++qq) {
            int t = t0 + g * 8 + qq;
            float acc = 0.f;
            #pragma unroll
            for (int j = 0; j < 4; ++j) {
                int h = w * 4 + j;
                size_t bht = (size_t)(b * H_ + h) * T_ + t;
                float s  = s_buf[bht];
                float vv = bfu2f(v_buf[bht * D_ + lane]);
                float mn = fmaxf(m[j], s);
                float ea = __expf(m[j] - mn);
                float eb = __expf(s - mn);
                u[j]  = u[j] * ea + eb;
                ws[j] = ws[j] * ea + vv * eb;
                m[j]  = mn;
                acc += ws[j] / u[j];
            }
            part[w][qq][lane] = acc;
        }
        __syncthreads();
        {
            int e  = threadIdx.x;
            int tt = e >> 6, d = e & 63;
            float sum = part[0][tt][d] + part[1][tt][d]
                      + part[2][tt][d] + part[3][tt][d];
            out[((size_t)b * T_ + (t0 + g * 8 + tt)) * D_ + d] = sum * (1.f / 16.f);
        }
        {
            int e  = threadIdx.x + 256;
            int tt = e >> 6, d = e & 63;
            float sum = part[0][tt][d] + part[1][tt][d]
                      + part[2][tt][d] + part[3][tt][d];
            out[((size_t)b * T_ + (t0 + g * 8 + tt)) * D_ + d] = sum * (1.f / 16.f);
        }
        __syncthreads();
    }
}

// ---------------------------------------------------------------------------
extern "C" void kernel_launch(void* const* d_in, const int* in_sizes, int n_in,
                              void* d_out, int out_size, void* d_ws, size_t ws_size,
                              hipStream_t stream) {
    const float* A  = (const float*)d_in[0];  // inputs (B,T,I)
    const float* Bm = (const float*)d_in[1];  // kv_kernel (I,H,D,2)
    const float* q  = (const float*)d_in[2];  // q_kernel (H,D)
    float* out = (float*)d_out;

    // workspace layout: v (bf16) | s | agg_m | agg_u | agg_w | A2 | B2T
    ushort* v_buf = (ushort*)d_ws;
    float*  s_buf = (float*)(v_buf + (size_t)B_ * H_ * T_ * D_);
    float*  agg_m = s_buf + (size_t)B_ * H_ * T_;
    float*  agg_u = agg_m + B_ * H_ * C_;
    float*  agg_w = agg_u + B_ * H_ * C_;
    ushort* A2    = (ushort*)(agg_w + (size_t)B_ * H_ * C_ * D_);
    ushort* B2T   = A2 + (size_t)M_ * 1024;

    size_t need = (size_t)B_ * H_ * T_ * D_ * 2
                + ((size_t)262144 + 4096 + 4096 + 262144) * 4
                + ((size_t)M_ * 1024 + (size_t)2048 * 1024) * 2;

    if (ws_size >= need) {
        convert_fused_kernel<<<16896, 256, 0, stream>>>(A, A2, Bm, B2T);
        gemm_mfma8_kernel<<<512, 512, 0, stream>>>(A2, B2T, q, v_buf, s_buf,
                                                   agg_m, agg_u, agg_w);
    } else {
        dim3 ggrid(H_, M_ / TILE_M);
        gemm_kv_kernel<<<ggrid, 256, 0, stream>>>(A, Bm, q, v_buf, s_buf);
        chunk_agg_kernel<<<B_ * H_ * C_, 64, 0, stream>>>(s_buf, v_buf,
                                                          agg_m, agg_u, agg_w);
    }
    chunk_prefix_kernel<<<B_ * H_, 64, 0, stream>>>(agg_m, agg_u, agg_w);
    scan_apply_kernel<<<B_ * C_, 256, 0, stream>>>(s_buf, v_buf, agg_m, agg_u, agg_w, out);
}